// Round 9
// baseline (138.935 us; speedup 1.0000x reference)
//
#include <hip/hip_runtime.h>
#include <stdint.h>

#define HW 65536   // 256*256
#define C_ 64

typedef __attribute__((ext_vector_type(8))) short short8;
typedef __attribute__((ext_vector_type(4))) float f32x4;
typedef long long i64;

#define MFMA16(a, b, c) __builtin_amdgcn_mfma_f32_16x16x32_bf16((a), (b), (c), 0, 0, 0)
#define MFMA8(a, b, c)  __builtin_amdgcn_mfma_f32_16x16x32_fp8_fp8((a), (b), (c), 0, 0, 0)

union U16x8 { uint4 q; short8 v; uint32_t u[4]; };
union PU { uint32_t u[2]; i64 q; };

__device__ inline uint32_t pack_bf16(float lo, float hi) {
  uint32_t ul = __float_as_uint(lo), uh = __float_as_uint(hi);
  ul = (ul + 0x7fffu + ((ul >> 16) & 1u)) >> 16;
  uh = (uh + 0x7fffu + ((uh >> 16) & 1u)) >> 16;
  return ul | (uh << 16);
}
__device__ inline i64 ld8f8(const uint8_t* p) { return *(const i64*)p; }
__device__ inline uint32_t pk4f8(float a, float b, float c, float d) {
  uint32_t v = __builtin_amdgcn_cvt_pk_fp8_f32(a, b, 0, false);
  v = __builtin_amdgcn_cvt_pk_fp8_f32(c, d, v, true);
  return v;
}

// fp8 Q/S tile: byte index [pix][c], XOR swizzle (8B granule)
__device__ inline int qf_idx(int p, int c) { return p * 64 + (c ^ ((p & 7) << 3)); }
// fp8 V tile: byte offset [c][j]
__device__ inline int vf_idx(int c, int j) { return c * 256 + (j ^ ((c & 7) << 3)); }

__global__ __launch_bounds__(512, 4) void SCAM_73151882985874_kernel(
    const float* __restrict__ x, const float* __restrict__ res_enc,
    const float* __restrict__ tr_feat,
    const float* __restrict__ Wl1, const float* __restrict__ bl1,
    const float* __restrict__ Wr1, const float* __restrict__ br1,
    const float* __restrict__ Wl2, const float* __restrict__ bl2,
    const float* __restrict__ Wr2, const float* __restrict__ br2,
    const float* __restrict__ beta1, const float* __restrict__ gamma1,
    const float* __restrict__ beta3, const float* __restrict__ gamma3,
    float* __restrict__ out)
{
  __shared__ __align__(16) uint8_t sQ[16384];    // Q  fp8 [pix][c] (unscaled)
  __shared__ __align__(16) uint8_t sS[16384];    // S  fp8 [pix][c]
  __shared__ __align__(16) uint8_t sVL[16384];   // bufL fp8 [c][j]
  __shared__ __align__(16) uint8_t sVR[16384];   // bufR fp8 [c][j]
  // NO P scratch: P redistributed in-register via ds_bpermute.

  const int tid = threadIdx.x;
  const int wid = tid >> 6, lane = tid & 63, g = lane >> 4, li = lane & 15;
  const int bb = blockIdx.x >> 8, hh = blockIdx.x & 255;
  const float yy = (float)hh * (2.0f / 255.0f) - 1.0f;
  const float rr = fabsf(yy - 0.5f);

  const size_t rowoff = (size_t)hh * 256;
  const float* xl  = x + ((size_t)bb * C_) * HW + rowoff;
  const float* xr  = x + ((size_t)(2 + bb) * C_) * HW + rowoff;
  const float* trl = tr_feat + ((size_t)bb * C_) * HW + rowoff;
  const float* trr = tr_feat + ((size_t)(2 + bb) * C_) * HW + rowoff;
  const float* rel = res_enc + ((size_t)bb * C_) * HW + rowoff;
  const float* rer = res_enc + ((size_t)(2 + bb) * C_) * HW + rowoff;
  float* outL = out + ((size_t)bb * C_) * HW + rowoff;
  float* outR = out + ((size_t)(2 + bb) * C_) * HW + rowoff;

  // P-redistribution lane constants (loop-invariant):
  // target lane (g,li) pulls dword-low from lane 2(g&1)*16+li, dword-high from
  // lane (2(g&1)+1)*16+li; register D[g>>1]. bpermute addr = srclane*4.
  const int addr_lo = ((((g & 1) << 1) << 4) + li) << 2;
  const int addr_hi = addr_lo + 64;
  const bool hiD = (g >= 2);

  auto ldXfrag = [&](const float* __restrict__ src, int pix, int c0) -> short8 {
    const float* s = src + (size_t)c0 * HW + pix;
    U16x8 t8;
    t8.u[0] = pack_bf16(s[0],              s[(size_t)HW]);
    t8.u[1] = pack_bf16(s[2 * (size_t)HW], s[3 * (size_t)HW]);
    t8.u[2] = pack_bf16(s[4 * (size_t)HW], s[5 * (size_t)HW]);
    t8.u[3] = pack_bf16(s[6 * (size_t)HW], s[7 * (size_t)HW]);
    return t8.v;
  };

  auto conv_one = [&](const float* __restrict__ Wm, int ldw,
                      const float* __restrict__ bias, const float* __restrict__ mod,
                      const float* __restrict__ E, int coord,
                      const short8 bx[2][2], uint8_t* dstQS, uint8_t* dstV) {
    #pragma unroll
    for (int ct = 0; ct < 4; ++ct) {
      short8 af0, af1;
      {
        const float* wr = Wm + (size_t)(ct * 16 + li) * ldw + g * 8;
        U16x8 t8;
        t8.u[0] = pack_bf16(wr[0], wr[1]); t8.u[1] = pack_bf16(wr[2], wr[3]);
        t8.u[2] = pack_bf16(wr[4], wr[5]); t8.u[3] = pack_bf16(wr[6], wr[7]);
        af0 = t8.v;
        const float* w2 = wr + 32;
        t8.u[0] = pack_bf16(w2[0], w2[1]); t8.u[1] = pack_bf16(w2[2], w2[3]);
        t8.u[2] = pack_bf16(w2[4], w2[5]); t8.u[3] = pack_bf16(w2[6], w2[7]);
        af1 = t8.v;
      }
      float be[4], md[4];
      #pragma unroll
      for (int r = 0; r < 4; ++r) {
        int c = ct * 16 + 4 * g + r;
        float b = bias[c];
        if (coord) b += Wm[(size_t)c * ldw + 64] * yy + Wm[(size_t)c * ldw + 65] * rr;
        be[r] = b;
        md[r] = mod[c];
      }
      #pragma unroll
      for (int ptl = 0; ptl < 2; ++ptl) {
        int pix = wid * 32 + ptl * 16 + li;
        float ev[4];
        #pragma unroll
        for (int r = 0; r < 4; ++r)
          ev[r] = E[(size_t)(ct * 16 + 4 * g + r) * HW + pix];
        f32x4 acc = {0.f, 0.f, 0.f, 0.f};
        acc = MFMA16(af0, bx[ptl][0], acc);
        acc = MFMA16(af1, bx[ptl][1], acc);
        float v[4];
        #pragma unroll
        for (int r = 0; r < 4; ++r) v[r] = acc[r] + be[r] + md[r] * ev[r];
        if (dstV) {
          uint32_t pk = pk4f8(v[0], v[1], v[2], v[3]);
          #pragma unroll
          for (int r = 0; r < 4; ++r)
            dstV[vf_idx(ct * 16 + 4 * g + r, pix)] = (uint8_t)(pk >> (8 * r));
        } else {
          *(uint32_t*)&dstQS[qf_idx(pix, ct * 16 + 4 * g)] = pk4f8(v[0], v[1], v[2], v[3]);
        }
      }
    }
  };

  // ---------- conv phase (one barrier after) ----------
  {
    short8 bx[2][2];
    #pragma unroll
    for (int ptl = 0; ptl < 2; ++ptl) {
      int pix = wid * 32 + ptl * 16 + li;
      bx[ptl][0] = ldXfrag(xl, pix, g * 8);
      bx[ptl][1] = ldXfrag(xl, pix, 32 + g * 8);
    }
    conv_one(Wl1, 66, bl1, beta1,  trl, 1, bx, sQ,  nullptr);  // Q
    conv_one(Wl2, 64, bl2, gamma1, rel, 0, bx, nullptr, sVL);  // bufL
  }
  {
    short8 bx[2][2];
    #pragma unroll
    for (int ptl = 0; ptl < 2; ++ptl) {
      int pix = wid * 32 + ptl * 16 + li;
      bx[ptl][0] = ldXfrag(xr, pix, g * 8);
      bx[ptl][1] = ldXfrag(xr, pix, 32 + g * 8);
    }
    conv_one(Wr1, 66, br1, beta1,  trr, 1, bx, sS,  nullptr);  // S
    conv_one(Wr2, 64, br2, gamma1, rer, 0, bx, nullptr, sVR);  // bufR
  }
  __syncthreads();   // the ONLY barrier

  const int j0 = wid * 32;

  // ---------- pass 2: out_R cols = own 32 pixels; sum over a >= col ----------
  {
    i64 bS00 = ld8f8(&sS[qf_idx(j0 + li, g * 8)]);
    i64 bS01 = ld8f8(&sS[qf_idx(j0 + li, 32 + g * 8)]);
    i64 bS10 = ld8f8(&sS[qf_idx(j0 + 16 + li, g * 8)]);
    i64 bS11 = ld8f8(&sS[qf_idx(j0 + 16 + li, 32 + g * 8)]);
    f32x4 acc[4][2];
    #pragma unroll
    for (int ct = 0; ct < 4; ++ct) { acc[ct][0] = (f32x4){0,0,0,0}; acc[ct][1] = (f32x4){0,0,0,0}; }
    float zp0 = 0.f, zp1 = 0.f;

    for (int ip = wid; ip < 8; ++ip) {
      i64 aQ00 = ld8f8(&sQ[qf_idx(ip * 32 + li, g * 8)]);
      i64 aQ01 = ld8f8(&sQ[qf_idx(ip * 32 + li, 32 + g * 8)]);
      i64 aQ10 = ld8f8(&sQ[qf_idx(ip * 32 + 16 + li, g * 8)]);
      i64 aQ11 = ld8f8(&sQ[qf_idx(ip * 32 + 16 + li, 32 + g * 8)]);
      i64 aV0 = ld8f8(&sVL[vf_idx(li,      ip * 32 + g * 8)]);
      i64 aV1 = ld8f8(&sVL[vf_idx(16 + li, ip * 32 + g * 8)]);
      i64 aV2 = ld8f8(&sVL[vf_idx(32 + li, ip * 32 + g * 8)]);
      i64 aV3 = ld8f8(&sVL[vf_idx(48 + li, ip * 32 + g * 8)]);
      const int a0 = ip * 32 + 4 * g;
      #pragma unroll
      for (int jt = 0; jt < 2; ++jt) {
        const int jj = j0 + jt * 16 + li;
        const i64 b0 = jt ? bS10 : bS00;
        const i64 b1 = jt ? bS11 : bS01;
        f32x4 s0 = {0.f, 0.f, 0.f, 0.f};
        s0 = MFMA8(aQ00, b0, s0); s0 = MFMA8(aQ01, b1, s0);
        f32x4 s1 = {0.f, 0.f, 0.f, 0.f};
        s1 = MFMA8(aQ10, b0, s1); s1 = MFMA8(aQ11, b1, s1);
        float ps = 0.f, p0[4], p1[4];
        #pragma unroll
        for (int r = 0; r < 4; ++r) {
          p0[r] = (a0 + r >= jj)      ? __expf(s0[r] * 0.125f) : 0.f;
          p1[r] = (a0 + 16 + r >= jj) ? __expf(s1[r] * 0.125f) : 0.f;
          ps += p0[r] + p1[r];
        }
        if (jt == 0) zp0 += ps; else zp1 += ps;
        uint32_t D0 = pk4f8(p0[0], p0[1], p0[2], p0[3]);
        uint32_t D1 = pk4f8(p1[0], p1[1], p1[2], p1[3]);
        int w00 = __builtin_amdgcn_ds_bpermute(addr_lo, (int)D0);
        int w01 = __builtin_amdgcn_ds_bpermute(addr_lo, (int)D1);
        int w10 = __builtin_amdgcn_ds_bpermute(addr_hi, (int)D0);
        int w11 = __builtin_amdgcn_ds_bpermute(addr_hi, (int)D1);
        PU t;
        t.u[0] = hiD ? (uint32_t)w01 : (uint32_t)w00;
        t.u[1] = hiD ? (uint32_t)w11 : (uint32_t)w10;
        const i64 bP = t.q;
        acc[0][jt] = MFMA8(aV0, bP, acc[0][jt]);
        acc[1][jt] = MFMA8(aV1, bP, acc[1][jt]);
        acc[2][jt] = MFMA8(aV2, bP, acc[2][jt]);
        acc[3][jt] = MFMA8(aV3, bP, acc[3][jt]);
      }
    }
    zp0 += __shfl_xor(zp0, 16); zp0 += __shfl_xor(zp0, 32);
    zp1 += __shfl_xor(zp1, 16); zp1 += __shfl_xor(zp1, 32);
    #pragma unroll
    for (int jt = 0; jt < 2; ++jt) {
      float invz = 1.0f / (jt == 0 ? zp0 : zp1);
      int j = j0 + jt * 16 + li;
      #pragma unroll
      for (int ct = 0; ct < 4; ++ct)
        #pragma unroll
        for (int r = 0; r < 4; ++r) {
          int c = ct * 16 + 4 * g + r;
          outR[(size_t)c * HW + j] =
              fmaf(gamma3[c], acc[ct][jt][r] * invz, xr[(size_t)c * HW + j]);
        }
    }
  }

  // ---------- pass 1: out_L cols = own 32 pixels; sum over a <= col ----------
  {
    i64 bQ00 = ld8f8(&sQ[qf_idx(j0 + li, g * 8)]);
    i64 bQ01 = ld8f8(&sQ[qf_idx(j0 + li, 32 + g * 8)]);
    i64 bQ10 = ld8f8(&sQ[qf_idx(j0 + 16 + li, g * 8)]);
    i64 bQ11 = ld8f8(&sQ[qf_idx(j0 + 16 + li, 32 + g * 8)]);
    f32x4 acc[4][2];
    #pragma unroll
    for (int ct = 0; ct < 4; ++ct) { acc[ct][0] = (f32x4){0,0,0,0}; acc[ct][1] = (f32x4){0,0,0,0}; }
    float zp0 = 0.f, zp1 = 0.f;

    for (int jp = 0; jp <= wid; ++jp) {
      i64 aS00 = ld8f8(&sS[qf_idx(jp * 32 + li, g * 8)]);
      i64 aS01 = ld8f8(&sS[qf_idx(jp * 32 + li, 32 + g * 8)]);
      i64 aS10 = ld8f8(&sS[qf_idx(jp * 32 + 16 + li, g * 8)]);
      i64 aS11 = ld8f8(&sS[qf_idx(jp * 32 + 16 + li, 32 + g * 8)]);
      i64 aV0 = ld8f8(&sVR[vf_idx(li,      jp * 32 + g * 8)]);
      i64 aV1 = ld8f8(&sVR[vf_idx(16 + li, jp * 32 + g * 8)]);
      i64 aV2 = ld8f8(&sVR[vf_idx(32 + li, jp * 32 + g * 8)]);
      i64 aV3 = ld8f8(&sVR[vf_idx(48 + li, jp * 32 + g * 8)]);
      const int a0 = jp * 32 + 4 * g;
      #pragma unroll
      for (int itl = 0; itl < 2; ++itl) {
        const int ii = j0 + itl * 16 + li;
        const i64 b0 = itl ? bQ10 : bQ00;
        const i64 b1 = itl ? bQ11 : bQ01;
        f32x4 s0 = {0.f, 0.f, 0.f, 0.f};
        s0 = MFMA8(aS00, b0, s0); s0 = MFMA8(aS01, b1, s0);
        f32x4 s1 = {0.f, 0.f, 0.f, 0.f};
        s1 = MFMA8(aS10, b0, s1); s1 = MFMA8(aS11, b1, s1);
        float ps = 0.f, p0[4], p1[4];
        #pragma unroll
        for (int r = 0; r < 4; ++r) {
          p0[r] = (a0 + r <= ii)      ? __expf(s0[r] * 0.125f) : 0.f;
          p1[r] = (a0 + 16 + r <= ii) ? __expf(s1[r] * 0.125f) : 0.f;
          ps += p0[r] + p1[r];
        }
        if (itl == 0) zp0 += ps; else zp1 += ps;
        uint32_t D0 = pk4f8(p0[0], p0[1], p0[2], p0[3]);
        uint32_t D1 = pk4f8(p1[0], p1[1], p1[2], p1[3]);
        int w00 = __builtin_amdgcn_ds_bpermute(addr_lo, (int)D0);
        int w01 = __builtin_amdgcn_ds_bpermute(addr_lo, (int)D1);
        int w10 = __builtin_amdgcn_ds_bpermute(addr_hi, (int)D0);
        int w11 = __builtin_amdgcn_ds_bpermute(addr_hi, (int)D1);
        PU t;
        t.u[0] = hiD ? (uint32_t)w01 : (uint32_t)w00;
        t.u[1] = hiD ? (uint32_t)w11 : (uint32_t)w10;
        const i64 bP = t.q;
        acc[0][itl] = MFMA8(aV0, bP, acc[0][itl]);
        acc[1][itl] = MFMA8(aV1, bP, acc[1][itl]);
        acc[2][itl] = MFMA8(aV2, bP, acc[2][itl]);
        acc[3][itl] = MFMA8(aV3, bP, acc[3][itl]);
      }
    }
    zp0 += __shfl_xor(zp0, 16); zp0 += __shfl_xor(zp0, 32);
    zp1 += __shfl_xor(zp1, 16); zp1 += __shfl_xor(zp1, 32);
    #pragma unroll
    for (int itl = 0; itl < 2; ++itl) {
      float invz = 1.0f / (itl == 0 ? zp0 : zp1);
      int i = j0 + itl * 16 + li;
      #pragma unroll
      for (int ct = 0; ct < 4; ++ct)
        #pragma unroll
        for (int r = 0; r < 4; ++r) {
          int c = ct * 16 + 4 * g + r;
          outL[(size_t)c * HW + i] =
              fmaf(beta3[c], acc[ct][itl][r] * invz, xl[(size_t)c * HW + i]);
        }
    }
  }
}

extern "C" void kernel_launch(void* const* d_in, const int* in_sizes, int n_in,
                              void* d_out, int out_size, void* d_ws, size_t ws_size,
                              hipStream_t stream) {
  const float* x       = (const float*)d_in[0];
  const float* res_enc = (const float*)d_in[1];
  const float* tr_feat = (const float*)d_in[2];
  const float* Wl1     = (const float*)d_in[3];
  const float* bl1     = (const float*)d_in[4];
  const float* Wr1     = (const float*)d_in[5];
  const float* br1     = (const float*)d_in[6];
  const float* Wl2     = (const float*)d_in[7];
  const float* bl2     = (const float*)d_in[8];
  const float* Wr2     = (const float*)d_in[9];
  const float* br2     = (const float*)d_in[10];
  const float* beta1   = (const float*)d_in[11];
  const float* gamma1  = (const float*)d_in[12];
  const float* beta3   = (const float*)d_in[13];
  const float* gamma3  = (const float*)d_in[14];
  float* outp = (float*)d_out;

  dim3 grid(512);    // 2 left-batches x 256 rows
  dim3 block(512);   // 8 waves, one 32-pixel column tile each
  SCAM_73151882985874_kernel<<<grid, block, 0, stream>>>(
      x, res_enc, tr_feat, Wl1, bl1, Wr1, br1, Wl2, bl2, Wr2, br2,
      beta1, gamma1, beta3, gamma3, outp);
}

// Round 10
// 73.057 us; speedup vs baseline: 1.9017x; 1.9017x over previous
//
#include <hip/hip_runtime.h>
#include <stdint.h>

#define HW 65536   // 256*256
#define C_ 64

typedef __attribute__((ext_vector_type(8))) short short8;
typedef __attribute__((ext_vector_type(4))) float f32x4;
typedef long long i64;

#define MFMA16(a, b, c) __builtin_amdgcn_mfma_f32_16x16x32_bf16((a), (b), (c), 0, 0, 0)
#define MFMA8(a, b, c)  __builtin_amdgcn_mfma_f32_16x16x32_fp8_fp8((a), (b), (c), 0, 0, 0)

union U16x8 { uint4 q; short8 v; uint32_t u[4]; };
union PU { uint32_t u[2]; i64 q; };

__device__ inline uint32_t pack_bf16(float lo, float hi) {
  uint32_t ul = __float_as_uint(lo), uh = __float_as_uint(hi);
  ul = (ul + 0x7fffu + ((ul >> 16) & 1u)) >> 16;
  uh = (uh + 0x7fffu + ((uh >> 16) & 1u)) >> 16;
  return ul | (uh << 16);
}
__device__ inline short8 ld8bf(const uint16_t* p) {
  U16x8 t; t.q = *(const uint4*)p; return t.v;
}
__device__ inline i64 ld8f8(const uint8_t* p) { return *(const i64*)p; }
__device__ inline uint32_t pk4f8(float a, float b, float c, float d) {
  uint32_t v = __builtin_amdgcn_cvt_pk_fp8_f32(a, b, 0, false);
  v = __builtin_amdgcn_cvt_pk_fp8_f32(c, d, v, true);
  return v;
}

// fp8 Q/S tile: byte index [pix][c], XOR swizzle (8B granule)
__device__ inline int qf_idx(int p, int c) { return p * 64 + (c ^ ((p & 7) << 3)); }
// fp8 V tile: byte offset [c][j]
__device__ inline int vf_idx(int c, int j) { return c * 256 + (j ^ ((c & 7) << 3)); }
// bf16 W tile: elem index [r][k], XOR swizzle (8-elem granule)
__device__ inline int wf_idx(int r, int k) { return r * 64 + (k ^ ((r & 7) << 3)); }

// (512,2): r6/r8/r9 proved (512,4) forces a 64-arch-VGPR cap -> spills that
// cost more than 2-blocks/CU pays. Accept 1 block/CU; minimize per-wave work.
__global__ __launch_bounds__(512, 2) void SCAM_73151882985874_kernel(
    const float* __restrict__ x, const float* __restrict__ res_enc,
    const float* __restrict__ tr_feat,
    const float* __restrict__ Wl1, const float* __restrict__ bl1,
    const float* __restrict__ Wr1, const float* __restrict__ br1,
    const float* __restrict__ Wl2, const float* __restrict__ bl2,
    const float* __restrict__ Wr2, const float* __restrict__ br2,
    const float* __restrict__ beta1, const float* __restrict__ gamma1,
    const float* __restrict__ beta3, const float* __restrict__ gamma3,
    float* __restrict__ out)
{
  __shared__ __align__(16) uint8_t sQ[16384];    // Q  fp8 [pix][c] (unscaled)
  __shared__ __align__(16) uint8_t sS[16384];    // S  fp8 [pix][c]
  __shared__ __align__(16) uint8_t sVL[16384];   // bufL fp8 [c][j]
  __shared__ __align__(16) uint8_t sVR[16384];   // bufR fp8 [c][j]
  __shared__ __align__(16) uint16_t sW[16384];   // 4 x [64][64] bf16 W cores (32KB)

  const int tid = threadIdx.x;
  const int wid = tid >> 6, lane = tid & 63, g = lane >> 4, li = lane & 15;
  const int bb = blockIdx.x >> 8, hh = blockIdx.x & 255;
  const float yy = (float)hh * (2.0f / 255.0f) - 1.0f;
  const float rr = fabsf(yy - 0.5f);

  const size_t rowoff = (size_t)hh * 256;
  const float* xl  = x + ((size_t)bb * C_) * HW + rowoff;
  const float* xr  = x + ((size_t)(2 + bb) * C_) * HW + rowoff;
  const float* trl = tr_feat + ((size_t)bb * C_) * HW + rowoff;
  const float* trr = tr_feat + ((size_t)(2 + bb) * C_) * HW + rowoff;
  const float* rel = res_enc + ((size_t)bb * C_) * HW + rowoff;
  const float* rer = res_enc + ((size_t)(2 + bb) * C_) * HW + rowoff;
  float* outL = out + ((size_t)bb * C_) * HW + rowoff;
  float* outR = out + ((size_t)(2 + bb) * C_) * HW + rowoff;

  // ---------- Phase W: stage all 4 weight cores to LDS bf16 (once per block) ----------
  {
    const int r = tid >> 3, k0 = (tid & 7) * 8;
    const float* Ws[4] = {Wl1, Wr1, Wl2, Wr2};
    const int ldws[4] = {66, 66, 64, 64};
    #pragma unroll
    for (int m = 0; m < 4; ++m) {
      const float* src = Ws[m] + (size_t)r * ldws[m] + k0;
      U16x8 t8;
      t8.u[0] = pack_bf16(src[0], src[1]); t8.u[1] = pack_bf16(src[2], src[3]);
      t8.u[2] = pack_bf16(src[4], src[5]); t8.u[3] = pack_bf16(src[6], src[7]);
      *(uint4*)&sW[m * 4096 + wf_idx(r, k0)] = t8.q;
    }
  }

  // P-redistribution lane constants (verified r9, absmax unchanged):
  // lane (g,li) pulls dword-low from lane 2(g&1)*16+li, dword-high from lane
  // (2(g&1)+1)*16+li; selects D[g>>1]. bpermute addr = srclane*4.
  const int addr_lo = ((((g & 1) << 1) << 4) + li) << 2;
  const int addr_hi = addr_lo + 64;
  const bool hiD = (g >= 2);

  auto ldXfrag = [&](const float* __restrict__ src, int pix, int c0) -> short8 {
    const float* s = src + (size_t)c0 * HW + pix;
    U16x8 t8;
    t8.u[0] = pack_bf16(s[0],              s[(size_t)HW]);
    t8.u[1] = pack_bf16(s[2 * (size_t)HW], s[3 * (size_t)HW]);
    t8.u[2] = pack_bf16(s[4 * (size_t)HW], s[5 * (size_t)HW]);
    t8.u[3] = pack_bf16(s[6 * (size_t)HW], s[7 * (size_t)HW]);
    return t8.v;
  };

  // widx: index of the staged W core; Wc: f32 source for coord columns (or null)
  auto conv_one = [&](int widx, const float* __restrict__ Wc,
                      const float* __restrict__ bias, const float* __restrict__ mod,
                      const float* __restrict__ E,
                      const short8 bx[2][2], uint8_t* dstQS, uint8_t* dstV) {
    const uint16_t* wb = sW + widx * 4096;
    #pragma unroll
    for (int ct = 0; ct < 4; ++ct) {
      const int wr = ct * 16 + li;
      short8 af0 = ld8bf(&wb[wf_idx(wr, g * 8)]);
      short8 af1 = ld8bf(&wb[wf_idx(wr, 32 + g * 8)]);
      float be[4], md[4];
      #pragma unroll
      for (int r = 0; r < 4; ++r) {
        int c = ct * 16 + 4 * g + r;
        float b = bias[c];
        if (Wc) b += Wc[(size_t)c * 66 + 64] * yy + Wc[(size_t)c * 66 + 65] * rr;
        be[r] = b;
        md[r] = mod[c];
      }
      #pragma unroll
      for (int ptl = 0; ptl < 2; ++ptl) {
        int pix = wid * 32 + ptl * 16 + li;
        float ev[4];
        #pragma unroll
        for (int r = 0; r < 4; ++r)
          ev[r] = E[(size_t)(ct * 16 + 4 * g + r) * HW + pix];
        f32x4 acc = {0.f, 0.f, 0.f, 0.f};
        acc = MFMA16(af0, bx[ptl][0], acc);
        acc = MFMA16(af1, bx[ptl][1], acc);
        float v[4];
        #pragma unroll
        for (int r = 0; r < 4; ++r) v[r] = acc[r] + be[r] + md[r] * ev[r];
        if (dstV) {
          uint32_t pk = pk4f8(v[0], v[1], v[2], v[3]);
          #pragma unroll
          for (int r = 0; r < 4; ++r)
            dstV[vf_idx(ct * 16 + 4 * g + r, pix)] = (uint8_t)(pk >> (8 * r));
        } else {
          *(uint32_t*)&dstQS[qf_idx(pix, ct * 16 + 4 * g)] = pk4f8(v[0], v[1], v[2], v[3]);
        }
      }
    }
  };

  // ---------- conv phase ----------
  {
    short8 bx[2][2];
    #pragma unroll
    for (int ptl = 0; ptl < 2; ++ptl) {
      int pix = wid * 32 + ptl * 16 + li;
      bx[ptl][0] = ldXfrag(xl, pix, g * 8);
      bx[ptl][1] = ldXfrag(xl, pix, 32 + g * 8);
    }
    __syncthreads();   // W staged (bx loads overlap the wait)
    conv_one(0, Wl1, bl1, beta1,  trl, bx, sQ,  nullptr);  // Q
    conv_one(2, nullptr, bl2, gamma1, rel, bx, nullptr, sVL);  // bufL
  }
  {
    short8 bx[2][2];
    #pragma unroll
    for (int ptl = 0; ptl < 2; ++ptl) {
      int pix = wid * 32 + ptl * 16 + li;
      bx[ptl][0] = ldXfrag(xr, pix, g * 8);
      bx[ptl][1] = ldXfrag(xr, pix, 32 + g * 8);
    }
    conv_one(1, Wr1, br1, beta1,  trr, bx, sS,  nullptr);  // S
    conv_one(3, nullptr, br2, gamma1, rer, bx, nullptr, sVR);  // bufR
  }
  __syncthreads();

  const int j0 = wid * 32;

  // ---------- pass 2: out_R cols = own 32 pixels; sum over a >= col ----------
  {
    i64 bS00 = ld8f8(&sS[qf_idx(j0 + li, g * 8)]);
    i64 bS01 = ld8f8(&sS[qf_idx(j0 + li, 32 + g * 8)]);
    i64 bS10 = ld8f8(&sS[qf_idx(j0 + 16 + li, g * 8)]);
    i64 bS11 = ld8f8(&sS[qf_idx(j0 + 16 + li, 32 + g * 8)]);
    f32x4 acc[4][2];
    #pragma unroll
    for (int ct = 0; ct < 4; ++ct) { acc[ct][0] = (f32x4){0,0,0,0}; acc[ct][1] = (f32x4){0,0,0,0}; }
    float zp0 = 0.f, zp1 = 0.f;

    for (int ip = wid; ip < 8; ++ip) {
      i64 aQ00 = ld8f8(&sQ[qf_idx(ip * 32 + li, g * 8)]);
      i64 aQ01 = ld8f8(&sQ[qf_idx(ip * 32 + li, 32 + g * 8)]);
      i64 aQ10 = ld8f8(&sQ[qf_idx(ip * 32 + 16 + li, g * 8)]);
      i64 aQ11 = ld8f8(&sQ[qf_idx(ip * 32 + 16 + li, 32 + g * 8)]);
      i64 aV0 = ld8f8(&sVL[vf_idx(li,      ip * 32 + g * 8)]);
      i64 aV1 = ld8f8(&sVL[vf_idx(16 + li, ip * 32 + g * 8)]);
      i64 aV2 = ld8f8(&sVL[vf_idx(32 + li, ip * 32 + g * 8)]);
      i64 aV3 = ld8f8(&sVL[vf_idx(48 + li, ip * 32 + g * 8)]);
      const int a0 = ip * 32 + 4 * g;
      #pragma unroll
      for (int jt = 0; jt < 2; ++jt) {
        const int jj = j0 + jt * 16 + li;
        const i64 b0 = jt ? bS10 : bS00;
        const i64 b1 = jt ? bS11 : bS01;
        f32x4 s0 = {0.f, 0.f, 0.f, 0.f};
        s0 = MFMA8(aQ00, b0, s0); s0 = MFMA8(aQ01, b1, s0);
        f32x4 s1 = {0.f, 0.f, 0.f, 0.f};
        s1 = MFMA8(aQ10, b0, s1); s1 = MFMA8(aQ11, b1, s1);
        float ps = 0.f, p0[4], p1[4];
        #pragma unroll
        for (int r = 0; r < 4; ++r) {
          p0[r] = (a0 + r >= jj)      ? __expf(s0[r] * 0.125f) : 0.f;
          p1[r] = (a0 + 16 + r >= jj) ? __expf(s1[r] * 0.125f) : 0.f;
          ps += p0[r] + p1[r];
        }
        if (jt == 0) zp0 += ps; else zp1 += ps;
        uint32_t D0 = pk4f8(p0[0], p0[1], p0[2], p0[3]);
        uint32_t D1 = pk4f8(p1[0], p1[1], p1[2], p1[3]);
        int w00 = __builtin_amdgcn_ds_bpermute(addr_lo, (int)D0);
        int w01 = __builtin_amdgcn_ds_bpermute(addr_lo, (int)D1);
        int w10 = __builtin_amdgcn_ds_bpermute(addr_hi, (int)D0);
        int w11 = __builtin_amdgcn_ds_bpermute(addr_hi, (int)D1);
        PU t;
        t.u[0] = hiD ? (uint32_t)w01 : (uint32_t)w00;
        t.u[1] = hiD ? (uint32_t)w11 : (uint32_t)w10;
        const i64 bP = t.q;
        acc[0][jt] = MFMA8(aV0, bP, acc[0][jt]);
        acc[1][jt] = MFMA8(aV1, bP, acc[1][jt]);
        acc[2][jt] = MFMA8(aV2, bP, acc[2][jt]);
        acc[3][jt] = MFMA8(aV3, bP, acc[3][jt]);
      }
    }
    zp0 += __shfl_xor(zp0, 16); zp0 += __shfl_xor(zp0, 32);
    zp1 += __shfl_xor(zp1, 16); zp1 += __shfl_xor(zp1, 32);
    #pragma unroll
    for (int jt = 0; jt < 2; ++jt) {
      float invz = 1.0f / (jt == 0 ? zp0 : zp1);
      int j = j0 + jt * 16 + li;
      #pragma unroll
      for (int ct = 0; ct < 4; ++ct)
        #pragma unroll
        for (int r = 0; r < 4; ++r) {
          int c = ct * 16 + 4 * g + r;
          outR[(size_t)c * HW + j] =
              fmaf(gamma3[c], acc[ct][jt][r] * invz, xr[(size_t)c * HW + j]);
        }
    }
  }

  // ---------- pass 1: out_L cols = own 32 pixels; sum over a <= col ----------
  {
    i64 bQ00 = ld8f8(&sQ[qf_idx(j0 + li, g * 8)]);
    i64 bQ01 = ld8f8(&sQ[qf_idx(j0 + li, 32 + g * 8)]);
    i64 bQ10 = ld8f8(&sQ[qf_idx(j0 + 16 + li, g * 8)]);
    i64 bQ11 = ld8f8(&sQ[qf_idx(j0 + 16 + li, 32 + g * 8)]);
    f32x4 acc[4][2];
    #pragma unroll
    for (int ct = 0; ct < 4; ++ct) { acc[ct][0] = (f32x4){0,0,0,0}; acc[ct][1] = (f32x4){0,0,0,0}; }
    float zp0 = 0.f, zp1 = 0.f;

    for (int jp = 0; jp <= wid; ++jp) {
      i64 aS00 = ld8f8(&sS[qf_idx(jp * 32 + li, g * 8)]);
      i64 aS01 = ld8f8(&sS[qf_idx(jp * 32 + li, 32 + g * 8)]);
      i64 aS10 = ld8f8(&sS[qf_idx(jp * 32 + 16 + li, g * 8)]);
      i64 aS11 = ld8f8(&sS[qf_idx(jp * 32 + 16 + li, 32 + g * 8)]);
      i64 aV0 = ld8f8(&sVR[vf_idx(li,      jp * 32 + g * 8)]);
      i64 aV1 = ld8f8(&sVR[vf_idx(16 + li, jp * 32 + g * 8)]);
      i64 aV2 = ld8f8(&sVR[vf_idx(32 + li, jp * 32 + g * 8)]);
      i64 aV3 = ld8f8(&sVR[vf_idx(48 + li, jp * 32 + g * 8)]);
      const int a0 = jp * 32 + 4 * g;
      #pragma unroll
      for (int itl = 0; itl < 2; ++itl) {
        const int ii = j0 + itl * 16 + li;
        const i64 b0 = itl ? bQ10 : bQ00;
        const i64 b1 = itl ? bQ11 : bQ01;
        f32x4 s0 = {0.f, 0.f, 0.f, 0.f};
        s0 = MFMA8(aS00, b0, s0); s0 = MFMA8(aS01, b1, s0);
        f32x4 s1 = {0.f, 0.f, 0.f, 0.f};
        s1 = MFMA8(aS10, b0, s1); s1 = MFMA8(aS11, b1, s1);
        float ps = 0.f, p0[4], p1[4];
        #pragma unroll
        for (int r = 0; r < 4; ++r) {
          p0[r] = (a0 + r <= ii)      ? __expf(s0[r] * 0.125f) : 0.f;
          p1[r] = (a0 + 16 + r <= ii) ? __expf(s1[r] * 0.125f) : 0.f;
          ps += p0[r] + p1[r];
        }
        if (itl == 0) zp0 += ps; else zp1 += ps;
        uint32_t D0 = pk4f8(p0[0], p0[1], p0[2], p0[3]);
        uint32_t D1 = pk4f8(p1[0], p1[1], p1[2], p1[3]);
        int w00 = __builtin_amdgcn_ds_bpermute(addr_lo, (int)D0);
        int w01 = __builtin_amdgcn_ds_bpermute(addr_lo, (int)D1);
        int w10 = __builtin_amdgcn_ds_bpermute(addr_hi, (int)D0);
        int w11 = __builtin_amdgcn_ds_bpermute(addr_hi, (int)D1);
        PU t;
        t.u[0] = hiD ? (uint32_t)w01 : (uint32_t)w00;
        t.u[1] = hiD ? (uint32_t)w11 : (uint32_t)w10;
        const i64 bP = t.q;
        acc[0][itl] = MFMA8(aV0, bP, acc[0][itl]);
        acc[1][itl] = MFMA8(aV1, bP, acc[1][itl]);
        acc[2][itl] = MFMA8(aV2, bP, acc[2][itl]);
        acc[3][itl] = MFMA8(aV3, bP, acc[3][itl]);
      }
    }
    zp0 += __shfl_xor(zp0, 16); zp0 += __shfl_xor(zp0, 32);
    zp1 += __shfl_xor(zp1, 16); zp1 += __shfl_xor(zp1, 32);
    #pragma unroll
    for (int itl = 0; itl < 2; ++itl) {
      float invz = 1.0f / (itl == 0 ? zp0 : zp1);
      int i = j0 + itl * 16 + li;
      #pragma unroll
      for (int ct = 0; ct < 4; ++ct)
        #pragma unroll
        for (int r = 0; r < 4; ++r) {
          int c = ct * 16 + 4 * g + r;
          outL[(size_t)c * HW + i] =
              fmaf(beta3[c], acc[ct][itl][r] * invz, xl[(size_t)c * HW + i]);
        }
    }
  }
}

extern "C" void kernel_launch(void* const* d_in, const int* in_sizes, int n_in,
                              void* d_out, int out_size, void* d_ws, size_t ws_size,
                              hipStream_t stream) {
  const float* x       = (const float*)d_in[0];
  const float* res_enc = (const float*)d_in[1];
  const float* tr_feat = (const float*)d_in[2];
  const float* Wl1     = (const float*)d_in[3];
  const float* bl1     = (const float*)d_in[4];
  const float* Wr1     = (const float*)d_in[5];
  const float* br1     = (const float*)d_in[6];
  const float* Wl2     = (const float*)d_in[7];
  const float* bl2     = (const float*)d_in[8];
  const float* Wr2     = (const float*)d_in[9];
  const float* br2     = (const float*)d_in[10];
  const float* beta1   = (const float*)d_in[11];
  const float* gamma1  = (const float*)d_in[12];
  const float* beta3   = (const float*)d_in[13];
  const float* gamma3  = (const float*)d_in[14];
  float* outp = (float*)d_out;

  dim3 grid(512);    // 2 left-batches x 256 rows
  dim3 block(512);   // 8 waves, one 32-pixel column tile each
  SCAM_73151882985874_kernel<<<grid, block, 0, stream>>>(
      x, res_enc, tr_feat, Wl1, bl1, Wr1, br1, Wl2, bl2, Wr2, br2,
      beta1, gamma1, beta3, gamma3, outp);
}